// Round 17
// baseline (212.749 us; speedup 1.0000x reference)
//
#include <hip/hip_runtime.h>
#include <hip/hip_bf16.h>
#include <stdint.h>

#define N_NODES 100000
#define DIM     64
#define NRELS   16
#define NBASE   8
#define HDIM    128
#define NEDGE   3200000
#define KDIM    1024               /* NRELS*DIM */

#define CBSH    8                  /* 256 nodes per coarse bucket */
#define CBN     256
#define NCB     391                /* ceil(100000/256) */
#define BCAP    9216               /* bucket capacity (verified r6-r16) */
#define SEGPB   (CBN * NRELS)      /* 4096 fine segments per bucket */
#define REC_PAD 256
#define NOFS_STRIDE 257            /* per-bucket node offsets + end sentinel */

#define P1_BLOCKS 500
#define P1_EPT    25               /* 500*256*25 = 3.2M exact */

#define PRO_VEFF_BLKS 512
#define PRO_VTXB_BLKS 12500        /* N*DIM/2/256 */
#define PRO_BLKS (PRO_VEFF_BLKS + PRO_VTXB_BLKS + 2)

typedef __attribute__((ext_vector_type(8))) short  short8;
typedef __attribute__((ext_vector_type(4))) float  f32x4;

/* ---- ws layout (bytes) ---- */
#define OFF_VEFF  0u
#define OFF_VTXB  262144u                          /* N*DIM*2 = 12,800,000 */
#define OFF_BCUR  13062144u                        /* NCB ints (pad)       */
#define OFF_NOFS  13064192u                        /* NCB*257 ints (pad)   */
#define OFF_REC1  13473792u                        /* (NCB*BCAP+pad)*8     */
#define REC_BYTES ((size_t)(NCB * BCAP + REC_PAD) * 8u)
#define OFF_REC2  (13473792u + REC_BYTES)
#define WS_NEED   (OFF_REC2 + REC_BYTES)

static __device__ __forceinline__ unsigned short f2bf(float x) {
    union { float f; unsigned u; } t; t.f = x;
    unsigned u = t.u;
    unsigned r = u + 0x7FFFu + ((u >> 16) & 1u);   /* RNE */
    return (unsigned short)(r >> 16);
}

/* ---- kernel 1: merged prologue (verified r7-r16) ---- */
__global__ __launch_bounds__(256) void prologue(
        const float* __restrict__ W, const float* __restrict__ Wc,
        __hip_bfloat16* __restrict__ veff,
        const float* __restrict__ vert, unsigned* __restrict__ vb,
        int* __restrict__ bcur) {
    int b = blockIdx.x, t = threadIdx.x;
    if (b < PRO_VEFF_BLKS) {
        int idx = b * 256 + t;
        int c = idx >> 7;
        int h = idx & 127;
        float acc = 0.f;
#pragma unroll
        for (int bb = 0; bb < NBASE; ++bb)
            acc += Wc[(c & 15) * NBASE + bb] * W[(bb * DIM + (c >> 4)) * HDIM + h];
        int kt = c >> 5, ko = c & 31;
        int lane = ((ko >> 3) << 4) | (h & 15);
        int j = ko & 7;
        int hb = h >> 4;
        ((unsigned short*)veff)[(size_t)((kt * 8 + hb) * 64 + lane) * 8 + j] = f2bf(acc);
    } else if (b < PRO_VEFF_BLKS + PRO_VTXB_BLKS) {
        int i = (b - PRO_VEFF_BLKS) * 256 + t;     /* N*DIM/2 pairs exact */
        float2 f = ((const float2*)vert)[i];
        unsigned r;
        asm("v_cvt_pk_bf16_f32 %0, %1, %2" : "=v"(r) : "v"(f.x), "v"(f.y));
        vb[i] = r;
    } else {
        int i = (b - PRO_VEFF_BLKS - PRO_VTXB_BLKS) * 256 + t;
        if (i < NCB) bcur[i] = i * BCAP;
    }
}

/* ---- kernel 2: coarse scatter into fixed-capacity buckets (verified r6-r16) ---- */
__global__ __launch_bounds__(256) void pass1_scatter(
        const int* __restrict__ esrc, const int* __restrict__ edst,
        const int* __restrict__ erel, const float* __restrict__ eval,
        int* __restrict__ bcur, uint2* __restrict__ recs1) {
    __shared__ int lcnt[NCB], lbase[NCB];
    int t = threadIdx.x;
    int base = blockIdx.x * (256 * P1_EPT);
    for (int i = t; i < NCB; i += 256) lcnt[i] = 0;
    __syncthreads();
#pragma unroll 5
    for (int k = 0; k < P1_EPT; ++k)
        atomicAdd(&lcnt[edst[base + k * 256 + t] >> CBSH], 1);
    __syncthreads();
    for (int i = t; i < NCB; i += 256) {
        int c = lcnt[i];
        if (c > 0) lbase[i] = atomicAdd(&bcur[i], c);
        lcnt[i] = 0;                                /* reuse as local cursor */
    }
    __syncthreads();
#pragma unroll 5
    for (int k = 0; k < P1_EPT; ++k) {
        int e = base + k * 256 + t;
        int dst = edst[e];
        int cb = dst >> CBSH;
        int slot = atomicAdd(&lcnt[cb], 1);
        uint2 r;
        r.x = (unsigned)esrc[e] | ((unsigned)erel[e] << 17)
            | ((unsigned)(dst & (CBN - 1)) << 21);
        r.y = __float_as_uint(eval[e]);
        recs1[lbase[cb] + slot] = r;
    }
}

/* ---- kernel 3: fine scatter within L2-resident bucket window (verified r7-r16) ---- */
__global__ __launch_bounds__(256) void pass2_scatter(
        const uint2* __restrict__ recs1, const int* __restrict__ bcur,
        int* __restrict__ nofs, uint2* __restrict__ recs2) {
    __shared__ int cur[SEGPB];
    __shared__ int wsum[4];
    int t = threadIdx.x;
    int cb = blockIdx.x;
    int r0 = cb * BCAP;
    int r1 = bcur[cb];
    int rend = r0 + BCAP; if (r1 > rend) r1 = rend;
    for (int i = t; i < SEGPB; i += 256) cur[i] = 0;
    __syncthreads();
    for (int i = r0 + t; i < r1; i += 256) {
        unsigned rx = recs1[i].x;
        int lseg = (int)(((rx >> 21) & 255u) * 16u + ((rx >> 17) & 15u));
        atomicAdd(&cur[lseg], 1);
    }
    __syncthreads();
    int b0 = t * 16;
    int vals[16]; int tsum = 0;
#pragma unroll
    for (int k = 0; k < 16; ++k) { vals[k] = cur[b0 + k]; tsum += vals[k]; }
    int lane = t & 63, w = t >> 6;
    int x = tsum;
#pragma unroll
    for (int d = 1; d < 64; d <<= 1) { int y = __shfl_up(x, d); if (lane >= d) x += y; }
    if (lane == 63) wsum[w] = x;
    __syncthreads();
    int wadd = 0;
    for (int i = 0; i < w; ++i) wadd += wsum[i];
    int run = r0 + wadd + x - tsum;                 /* node t record start */
    nofs[cb * NOFS_STRIDE + t] = run;
#pragma unroll
    for (int k = 0; k < 16; ++k) { cur[b0 + k] = run; run += vals[k]; }
    if (t == 255) nofs[cb * NOFS_STRIDE + 256] = run;   /* bucket end */
    __syncthreads();
    for (int i = r0 + t; i < r1; i += 256) {
        uint2 r = recs1[i];
        int lseg = (int)(((r.x >> 21) & 255u) * 16u + ((r.x >> 17) & 15u));
        int pos = atomicAdd(&cur[lseg], 1);
        recs2[pos] = r;
    }
}

/* ---- kernel 4: fused branchless aggregate + MFMA GEMM ----
   r16 inner loop verbatim; geometry reshaped to 256 thr / 4 waves /
   16 nodes / 34.8KB LDS -> 4 blocks/CU (16 waves/CU, was 12.3).
   GEMM tail: each wave computes 2 h-blocks (w and w+4). ---- */
__global__ __launch_bounds__(256, 4) void fused_agg_gemm(
        const unsigned short* __restrict__ vtxb, const uint2* __restrict__ recs,
        const int* __restrict__ nofs, const __hip_bfloat16* __restrict__ veff,
        const float* __restrict__ bias, float* __restrict__ out) {
    __shared__ __align__(16) unsigned char smem[17 * 2048];   /* 16 A-rows + scratch */
    int t = threadIdx.x;
    int g = blockIdx.x;
    int w = t >> 6, lane = t & 63;
    int q = lane >> 4, p = lane & 15;
    int nloc = w * 4 + q;              /* 0..15 */
    int n = g * 16 + nloc;

    for (int i = t; i < 17 * 2048 / 16; i += 256)
        ((uint4*)smem)[i] = make_uint4(0, 0, 0, 0);
    __syncthreads();

    int cbn = n >> CBSH, lo = n & (CBN - 1);
    int e0 = nofs[cbn * NOFS_STRIDE + lo];
    int e1 = nofs[cbn * NOFS_STRIDE + lo + 1];

    /* per-lane LDS write bases: addr = (active?rowb2:scrb2) + (rel<<7) */
    unsigned rowb2 = (unsigned)nloc * 2048u
                   + ((unsigned)(p * 8) ^ ((unsigned)(nloc & 7) << 4));
    unsigned scrb2 = 16u * 2048u + (unsigned)(p * 8);

    f32x4 acc = (f32x4)0.f;
    int currel = -1;
    const uint2* vtx2 = (const uint2*)vtxb;
    unsigned up = (unsigned)p;

    uint2 r0, r1, r2, r3, r4, r5, r6, r7;
    r0 = recs[e0 + 0]; r1 = recs[e0 + 1]; r2 = recs[e0 + 2]; r3 = recs[e0 + 3];
    r4 = recs[e0 + 4]; r5 = recs[e0 + 5]; r6 = recs[e0 + 6]; r7 = recs[e0 + 7];

    for (int base = e0; __any(base < e1); base += 8) {
        bool a0 = (base + 0) < e1, a1 = (base + 1) < e1;
        bool a2 = (base + 2) < e1, a3 = (base + 3) < e1;
        bool a4 = (base + 4) < e1, a5 = (base + 5) < e1;
        bool a6 = (base + 6) < e1, a7 = (base + 7) < e1;
        uint2 v0 = vtx2[a0 ? ((r0.x & 0x1FFFFu) * 16u + up) : up];
        uint2 v1 = vtx2[a1 ? ((r1.x & 0x1FFFFu) * 16u + up) : up];
        uint2 v2 = vtx2[a2 ? ((r2.x & 0x1FFFFu) * 16u + up) : up];
        uint2 v3 = vtx2[a3 ? ((r3.x & 0x1FFFFu) * 16u + up) : up];
        uint2 v4 = vtx2[a4 ? ((r4.x & 0x1FFFFu) * 16u + up) : up];
        uint2 v5 = vtx2[a5 ? ((r5.x & 0x1FFFFu) * 16u + up) : up];
        uint2 v6 = vtx2[a6 ? ((r6.x & 0x1FFFFu) * 16u + up) : up];
        uint2 v7 = vtx2[a7 ? ((r7.x & 0x1FFFFu) * 16u + up) : up];
        int nb = base + 8;
        uint2 n0 = recs[nb + 0], n1 = recs[nb + 1], n2 = recs[nb + 2], n3 = recs[nb + 3];
        uint2 n4 = recs[nb + 4], n5 = recs[nb + 5], n6 = recs[nb + 6], n7 = recs[nb + 7];

#define PROC(K, RK, VK, AK)                                                   \
        {                                                                     \
            bool active = (AK);                                               \
            int rel = (int)((RK.x >> 17) & 15u);                              \
            float val = active ? __uint_as_float(RK.y) : 0.f;                 \
            bool chg = (rel != currel) && active;                             \
            float f0 = __uint_as_float(VK.x << 16);                           \
            float f1 = __uint_as_float(VK.x & 0xFFFF0000u);                   \
            float f2 = __uint_as_float(VK.y << 16);                           \
            float f3 = __uint_as_float(VK.y & 0xFFFF0000u);                   \
            float t0 = chg ? 0.f : acc[0];                                    \
            float t1 = chg ? 0.f : acc[1];                                    \
            float t2 = chg ? 0.f : acc[2];                                    \
            float t3 = chg ? 0.f : acc[3];                                    \
            acc[0] = fmaf(val, f0, t0);                                       \
            acc[1] = fmaf(val, f1, t1);                                       \
            acc[2] = fmaf(val, f2, t2);                                       \
            acc[3] = fmaf(val, f3, t3);                                       \
            currel = active ? rel : currel;                                   \
            unsigned addr = (active ? rowb2 : scrb2) + ((unsigned)rel << 7);  \
            unsigned lo_, hi_;                                                \
            asm("v_cvt_pk_bf16_f32 %0, %1, %2" : "=v"(lo_)                    \
                : "v"(acc[0]), "v"(acc[1]));                                  \
            asm("v_cvt_pk_bf16_f32 %0, %1, %2" : "=v"(hi_)                    \
                : "v"(acc[2]), "v"(acc[3]));                                  \
            *(uint2*)(smem + addr) = make_uint2(lo_, hi_);                    \
        }
        PROC(0, r0, v0, a0) PROC(1, r1, v1, a1) PROC(2, r2, v2, a2) PROC(3, r3, v3, a3)
        PROC(4, r4, v4, a4) PROC(5, r5, v5, a5) PROC(6, r6, v6, a6) PROC(7, r7, v7, a7)
#undef PROC
        r0 = n0; r1 = n1; r2 = n2; r3 = n3;
        r4 = n4; r5 = n5; r6 = n6; r7 = n7;
    }
    __syncthreads();

    /* ---- GEMM: [16 x 1024] @ veff[1024 x 128]; wave w owns h-blocks w, w+4 ---- */
    int l15 = lane & 15, lhi = lane >> 4;
    unsigned axor = (unsigned)((l15 & 7) << 4);
    f32x4 acc0 = (f32x4)0.f, acc1 = (f32x4)0.f;
#pragma unroll
    for (int kt = 0; kt < 32; ++kt) {
        short8 bf0 = ((const short8*)veff)[(size_t)(kt * 8 + w) * 64 + lane];
        short8 bf1 = ((const short8*)veff)[(size_t)(kt * 8 + w + 4) * 64 + lane];
        unsigned cbo = (unsigned)(kt * 64 + lhi * 16);
        short8 a0 = *(const short8*)(smem + (((unsigned)l15 * 2048 + cbo) ^ axor));
        acc0 = __builtin_amdgcn_mfma_f32_16x16x32_bf16(a0, bf0, acc0, 0, 0, 0);
        acc1 = __builtin_amdgcn_mfma_f32_16x16x32_bf16(a0, bf1, acc1, 0, 0, 0);
    }
    int h0 = w * 16 + l15;
    int h1 = (w + 4) * 16 + l15;
    float bv0 = bias[h0];
    float bv1 = bias[h1];
#pragma unroll
    for (int j = 0; j < 4; ++j) {
        out[(size_t)(g * 16 + lhi * 4 + j) * HDIM + h0] = acc0[j] + bv0;
        out[(size_t)(g * 16 + lhi * 4 + j) * HDIM + h1] = acc1[j] + bv1;
    }
}

/* ---------- slow fallback (only if ws too small) ---------- */
__global__ __launch_bounds__(256) void build_veff_plain(
        const float* __restrict__ W, const float* __restrict__ Wc,
        float* __restrict__ veff) {
    int idx = blockIdx.x * 256 + threadIdx.x;
    int c = idx >> 7, h = idx & 127;
    float acc = 0.f;
#pragma unroll
    for (int b = 0; b < NBASE; ++b)
        acc += Wc[(c & 15) * NBASE + b] * W[(b * DIM + (c >> 4)) * HDIM + h];
    veff[c * HDIM + h] = acc;
}
__global__ __launch_bounds__(256) void init_out_bias(
        const float* __restrict__ bias, float* __restrict__ out) {
    int idx = blockIdx.x * 256 + threadIdx.x;
    if (idx < N_NODES * HDIM) out[idx] = bias[idx & 127];
}
__global__ __launch_bounds__(128) void edge_slow(
        const float* __restrict__ vertex, const float* __restrict__ eval,
        const int* __restrict__ esrc, const int* __restrict__ edst,
        const int* __restrict__ erel, const float* __restrict__ veff,
        float* __restrict__ out) {
    int e = blockIdx.x;
    int h = threadIdx.x;
    __shared__ float vrow[DIM];
    int src = esrc[e], dst = edst[e], rel = erel[e];
    float val = eval[e];
    if (h < DIM) vrow[h] = vertex[(size_t)src * DIM + h];
    __syncthreads();
    float acc = 0.f;
#pragma unroll 8
    for (int d = 0; d < DIM; ++d)
        acc += vrow[d] * veff[(rel * DIM + d) * HDIM + h];
    atomicAdd(out + (size_t)dst * HDIM + h, val * acc);
}

extern "C" void kernel_launch(void* const* d_in, const int* in_sizes, int n_in,
                              void* d_out, int out_size, void* d_ws, size_t ws_size,
                              hipStream_t stream) {
    const float* vertex   = (const float*)d_in[0];
    const float* edge_val = (const float*)d_in[1];
    const float* W        = (const float*)d_in[2];
    const float* W_comp   = (const float*)d_in[3];
    const float* B        = (const float*)d_in[4];
    const int*   edge_src = (const int*)d_in[5];
    const int*   edge_dst = (const int*)d_in[6];
    const int*   edge_rel = (const int*)d_in[7];
    float* out = (float*)d_out;

    if (ws_size >= WS_NEED) {
        __hip_bfloat16* veff = (__hip_bfloat16*)((char*)d_ws + OFF_VEFF);
        unsigned* vtxb = (unsigned*)((char*)d_ws + OFF_VTXB);
        int*   bcur  = (int*)((char*)d_ws + OFF_BCUR);
        int*   nofs  = (int*)((char*)d_ws + OFF_NOFS);
        uint2* recs1 = (uint2*)((char*)d_ws + OFF_REC1);
        uint2* recs2 = (uint2*)((char*)d_ws + OFF_REC2);

        prologue<<<PRO_BLKS, 256, 0, stream>>>(W, W_comp, veff, vertex, vtxb, bcur);
        pass1_scatter<<<P1_BLOCKS, 256, 0, stream>>>(
            edge_src, edge_dst, edge_rel, edge_val, bcur, recs1);
        pass2_scatter<<<NCB, 256, 0, stream>>>(recs1, bcur, nofs, recs2);
        fused_agg_gemm<<<N_NODES / 16, 256, 0, stream>>>(
            (const unsigned short*)vtxb, recs2, nofs, veff, B, out);
    } else {
        float* veff = (float*)d_ws;
        build_veff_plain<<<KDIM * HDIM / 256, 256, 0, stream>>>(W, W_comp, veff);
        init_out_bias<<<(N_NODES * HDIM + 255) / 256, 256, 0, stream>>>(B, out);
        edge_slow<<<NEDGE, 128, 0, stream>>>(
            vertex, edge_val, edge_src, edge_dst, edge_rel, veff, out);
    }
}

// Round 18
// 193.921 us; speedup vs baseline: 1.0971x; 1.0971x over previous
//
#include <hip/hip_runtime.h>
#include <hip/hip_bf16.h>
#include <stdint.h>

#define N_NODES 100000
#define DIM     64
#define NRELS   16
#define NBASE   8
#define HDIM    128
#define NEDGE   3200000
#define KDIM    1024               /* NRELS*DIM */

#define CBSH    8                  /* 256 nodes per coarse bucket */
#define CBN     256
#define NCB     391                /* ceil(100000/256) */
#define BCAP    9216               /* bucket capacity (verified r6-r17) */
#define SEGPB   (CBN * NRELS)      /* 4096 fine segments per bucket */
#define REC_PAD 256
#define NOFS_STRIDE 257            /* per-bucket node offsets + end sentinel */

#define P1_BLOCKS 500
#define P1_EPT    25               /* 500*256*25 = 3.2M exact */

#define PRO_VEFF_BLKS 512
#define PRO_VTXB_BLKS 12500        /* N*DIM/2/256 */
#define PRO_BLKS (PRO_VEFF_BLKS + PRO_VTXB_BLKS + 2)

typedef __attribute__((ext_vector_type(8))) short  short8;
typedef __attribute__((ext_vector_type(4))) float  f32x4;

/* ---- ws layout (bytes) ---- */
#define OFF_VEFF  0u
#define OFF_VTXB  262144u                          /* N*DIM*2 = 12,800,000 */
#define OFF_BCUR  13062144u                        /* NCB ints (pad)       */
#define OFF_NOFS  13064192u                        /* NCB*257 ints (pad)   */
#define OFF_REC1  13473792u                        /* (NCB*BCAP+pad)*8     */
#define REC_BYTES ((size_t)(NCB * BCAP + REC_PAD) * 8u)
#define OFF_REC2  (13473792u + REC_BYTES)
#define WS_NEED   (OFF_REC2 + REC_BYTES)

static __device__ __forceinline__ unsigned short f2bf(float x) {
    union { float f; unsigned u; } t; t.f = x;
    unsigned u = t.u;
    unsigned r = u + 0x7FFFu + ((u >> 16) & 1u);   /* RNE */
    return (unsigned short)(r >> 16);
}

/* ---- kernel 1: merged prologue (verified r7-r16) ---- */
__global__ __launch_bounds__(256) void prologue(
        const float* __restrict__ W, const float* __restrict__ Wc,
        __hip_bfloat16* __restrict__ veff,
        const float* __restrict__ vert, unsigned* __restrict__ vb,
        int* __restrict__ bcur) {
    int b = blockIdx.x, t = threadIdx.x;
    if (b < PRO_VEFF_BLKS) {
        int idx = b * 256 + t;
        int c = idx >> 7;
        int h = idx & 127;
        float acc = 0.f;
#pragma unroll
        for (int bb = 0; bb < NBASE; ++bb)
            acc += Wc[(c & 15) * NBASE + bb] * W[(bb * DIM + (c >> 4)) * HDIM + h];
        int kt = c >> 5, ko = c & 31;
        int lane = ((ko >> 3) << 4) | (h & 15);
        int j = ko & 7;
        int hb = h >> 4;
        ((unsigned short*)veff)[(size_t)((kt * 8 + hb) * 64 + lane) * 8 + j] = f2bf(acc);
    } else if (b < PRO_VEFF_BLKS + PRO_VTXB_BLKS) {
        int i = (b - PRO_VEFF_BLKS) * 256 + t;     /* N*DIM/2 pairs exact */
        float2 f = ((const float2*)vert)[i];
        unsigned r;
        asm("v_cvt_pk_bf16_f32 %0, %1, %2" : "=v"(r) : "v"(f.x), "v"(f.y));
        vb[i] = r;
    } else {
        int i = (b - PRO_VEFF_BLKS - PRO_VTXB_BLKS) * 256 + t;
        if (i < NCB) bcur[i] = i * BCAP;
    }
}

/* ---- kernel 2: coarse scatter into fixed-capacity buckets (verified r6-r16) ---- */
__global__ __launch_bounds__(256) void pass1_scatter(
        const int* __restrict__ esrc, const int* __restrict__ edst,
        const int* __restrict__ erel, const float* __restrict__ eval,
        int* __restrict__ bcur, uint2* __restrict__ recs1) {
    __shared__ int lcnt[NCB], lbase[NCB];
    int t = threadIdx.x;
    int base = blockIdx.x * (256 * P1_EPT);
    for (int i = t; i < NCB; i += 256) lcnt[i] = 0;
    __syncthreads();
#pragma unroll 5
    for (int k = 0; k < P1_EPT; ++k)
        atomicAdd(&lcnt[edst[base + k * 256 + t] >> CBSH], 1);
    __syncthreads();
    for (int i = t; i < NCB; i += 256) {
        int c = lcnt[i];
        if (c > 0) lbase[i] = atomicAdd(&bcur[i], c);
        lcnt[i] = 0;                                /* reuse as local cursor */
    }
    __syncthreads();
#pragma unroll 5
    for (int k = 0; k < P1_EPT; ++k) {
        int e = base + k * 256 + t;
        int dst = edst[e];
        int cb = dst >> CBSH;
        int slot = atomicAdd(&lcnt[cb], 1);
        uint2 r;
        r.x = (unsigned)esrc[e] | ((unsigned)erel[e] << 17)
            | ((unsigned)(dst & (CBN - 1)) << 21);
        r.y = __float_as_uint(eval[e]);
        recs1[lbase[cb] + slot] = r;
    }
}

/* ---- kernel 3: fine scatter within L2-resident bucket window (verified r7-r16) ---- */
__global__ __launch_bounds__(256) void pass2_scatter(
        const uint2* __restrict__ recs1, const int* __restrict__ bcur,
        int* __restrict__ nofs, uint2* __restrict__ recs2) {
    __shared__ int cur[SEGPB];
    __shared__ int wsum[4];
    int t = threadIdx.x;
    int cb = blockIdx.x;
    int r0 = cb * BCAP;
    int r1 = bcur[cb];
    int rend = r0 + BCAP; if (r1 > rend) r1 = rend;
    for (int i = t; i < SEGPB; i += 256) cur[i] = 0;
    __syncthreads();
    for (int i = r0 + t; i < r1; i += 256) {
        unsigned rx = recs1[i].x;
        int lseg = (int)(((rx >> 21) & 255u) * 16u + ((rx >> 17) & 15u));
        atomicAdd(&cur[lseg], 1);
    }
    __syncthreads();
    int b0 = t * 16;
    int vals[16]; int tsum = 0;
#pragma unroll
    for (int k = 0; k < 16; ++k) { vals[k] = cur[b0 + k]; tsum += vals[k]; }
    int lane = t & 63, w = t >> 6;
    int x = tsum;
#pragma unroll
    for (int d = 1; d < 64; d <<= 1) { int y = __shfl_up(x, d); if (lane >= d) x += y; }
    if (lane == 63) wsum[w] = x;
    __syncthreads();
    int wadd = 0;
    for (int i = 0; i < w; ++i) wadd += wsum[i];
    int run = r0 + wadd + x - tsum;                 /* node t record start */
    nofs[cb * NOFS_STRIDE + t] = run;
#pragma unroll
    for (int k = 0; k < 16; ++k) { cur[b0 + k] = run; run += vals[k]; }
    if (t == 255) nofs[cb * NOFS_STRIDE + 256] = run;   /* bucket end */
    __syncthreads();
    for (int i = r0 + t; i < r1; i += 256) {
        uint2 r = recs1[i];
        int lseg = (int)(((r.x >> 21) & 255u) * 16u + ((r.x >> 17) & 15u));
        int pos = atomicAdd(&cur[lseg], 1);
        recs2[pos] = r;
    }
}

/* ---- kernel 4: fused branchless aggregate + MFMA GEMM ----
   r7 structure + waste-fetch elimination (r16-verified, 105us):
   inactive slots redirect their vertex gather to row 0 (L1-hit). ---- */
__global__ __launch_bounds__(512, 4) void fused_agg_gemm(
        const unsigned short* __restrict__ vtxb, const uint2* __restrict__ recs,
        const int* __restrict__ nofs, const __hip_bfloat16* __restrict__ veff,
        const float* __restrict__ bias, float* __restrict__ out) {
    __shared__ __align__(16) unsigned char smem[33 * 2048];   /* 32 A-rows + scratch */
    int t = threadIdx.x;
    int g = blockIdx.x;
    int w = t >> 6, lane = t & 63;
    int q = lane >> 4, p = lane & 15;
    int nloc = w * 4 + q;
    int n = g * 32 + nloc;

    for (int i = t; i < 33 * 2048 / 16; i += 512)
        ((uint4*)smem)[i] = make_uint4(0, 0, 0, 0);
    __syncthreads();

    int cbn = n >> CBSH, lo = n & (CBN - 1);
    int e0 = nofs[cbn * NOFS_STRIDE + lo];
    int e1 = nofs[cbn * NOFS_STRIDE + lo + 1];

    /* per-lane LDS write bases: addr = (active?rowb2:scrb2) + (rel<<7) */
    unsigned rowb2 = (unsigned)nloc * 2048u
                   + ((unsigned)(p * 8) ^ ((unsigned)(nloc & 7) << 4));
    unsigned scrb2 = 32u * 2048u + (unsigned)(p * 8);

    f32x4 acc = (f32x4)0.f;
    int currel = -1;
    const uint2* vtx2 = (const uint2*)vtxb;
    unsigned up = (unsigned)p;

    uint2 r0, r1, r2, r3, r4, r5, r6, r7;
    r0 = recs[e0 + 0]; r1 = recs[e0 + 1]; r2 = recs[e0 + 2]; r3 = recs[e0 + 3];
    r4 = recs[e0 + 4]; r5 = recs[e0 + 5]; r6 = recs[e0 + 6]; r7 = recs[e0 + 7];

    for (int base = e0; __any(base < e1); base += 8) {
        bool a0 = (base + 0) < e1, a1 = (base + 1) < e1;
        bool a2 = (base + 2) < e1, a3 = (base + 3) < e1;
        bool a4 = (base + 4) < e1, a5 = (base + 5) < e1;
        bool a6 = (base + 6) < e1, a7 = (base + 7) < e1;
        uint2 v0 = vtx2[a0 ? ((r0.x & 0x1FFFFu) * 16u + up) : up];
        uint2 v1 = vtx2[a1 ? ((r1.x & 0x1FFFFu) * 16u + up) : up];
        uint2 v2 = vtx2[a2 ? ((r2.x & 0x1FFFFu) * 16u + up) : up];
        uint2 v3 = vtx2[a3 ? ((r3.x & 0x1FFFFu) * 16u + up) : up];
        uint2 v4 = vtx2[a4 ? ((r4.x & 0x1FFFFu) * 16u + up) : up];
        uint2 v5 = vtx2[a5 ? ((r5.x & 0x1FFFFu) * 16u + up) : up];
        uint2 v6 = vtx2[a6 ? ((r6.x & 0x1FFFFu) * 16u + up) : up];
        uint2 v7 = vtx2[a7 ? ((r7.x & 0x1FFFFu) * 16u + up) : up];
        int nb = base + 8;
        uint2 n0 = recs[nb + 0], n1 = recs[nb + 1], n2 = recs[nb + 2], n3 = recs[nb + 3];
        uint2 n4 = recs[nb + 4], n5 = recs[nb + 5], n6 = recs[nb + 6], n7 = recs[nb + 7];

#define PROC(K, RK, VK, AK)                                                   \
        {                                                                     \
            bool active = (AK);                                               \
            int rel = (int)((RK.x >> 17) & 15u);                              \
            float val = active ? __uint_as_float(RK.y) : 0.f;                 \
            bool chg = (rel != currel) && active;                             \
            float f0 = __uint_as_float(VK.x << 16);                           \
            float f1 = __uint_as_float(VK.x & 0xFFFF0000u);                   \
            float f2 = __uint_as_float(VK.y << 16);                           \
            float f3 = __uint_as_float(VK.y & 0xFFFF0000u);                   \
            float t0 = chg ? 0.f : acc[0];                                    \
            float t1 = chg ? 0.f : acc[1];                                    \
            float t2 = chg ? 0.f : acc[2];                                    \
            float t3 = chg ? 0.f : acc[3];                                    \
            acc[0] = fmaf(val, f0, t0);                                       \
            acc[1] = fmaf(val, f1, t1);                                       \
            acc[2] = fmaf(val, f2, t2);                                       \
            acc[3] = fmaf(val, f3, t3);                                       \
            currel = active ? rel : currel;                                   \
            unsigned addr = (active ? rowb2 : scrb2) + ((unsigned)rel << 7);  \
            unsigned lo_, hi_;                                                \
            asm("v_cvt_pk_bf16_f32 %0, %1, %2" : "=v"(lo_)                    \
                : "v"(acc[0]), "v"(acc[1]));                                  \
            asm("v_cvt_pk_bf16_f32 %0, %1, %2" : "=v"(hi_)                    \
                : "v"(acc[2]), "v"(acc[3]));                                  \
            *(uint2*)(smem + addr) = make_uint2(lo_, hi_);                    \
        }
        PROC(0, r0, v0, a0) PROC(1, r1, v1, a1) PROC(2, r2, v2, a2) PROC(3, r3, v3, a3)
        PROC(4, r4, v4, a4) PROC(5, r5, v5, a5) PROC(6, r6, v6, a6) PROC(7, r7, v7, a7)
#undef PROC
        r0 = n0; r1 = n1; r2 = n2; r3 = n3;
        r4 = n4; r5 = n5; r6 = n6; r7 = n7;
    }
    __syncthreads();

    /* ---- GEMM: [32 x 1024] @ veff[1024 x 128]; wave w owns h-block w ---- */
    int l15 = lane & 15, lhi = lane >> 4;
    unsigned axor = (unsigned)((l15 & 7) << 4);
    f32x4 acc0 = (f32x4)0.f, acc1 = (f32x4)0.f;
#pragma unroll
    for (int kt = 0; kt < 32; ++kt) {
        short8 bf = ((const short8*)veff)[(size_t)(kt * 8 + w) * 64 + lane];
        unsigned cbo = (unsigned)(kt * 64 + lhi * 16);
        short8 a0 = *(const short8*)(smem + (((unsigned)l15 * 2048 + cbo) ^ axor));
        short8 a1 = *(const short8*)(smem + (((unsigned)(16 + l15) * 2048 + cbo) ^ axor));
        acc0 = __builtin_amdgcn_mfma_f32_16x16x32_bf16(a0, bf, acc0, 0, 0, 0);
        acc1 = __builtin_amdgcn_mfma_f32_16x16x32_bf16(a1, bf, acc1, 0, 0, 0);
    }
    int h = w * 16 + l15;
    float bv = bias[h];
#pragma unroll
    for (int j = 0; j < 4; ++j) {
        out[(size_t)(g * 32 + lhi * 4 + j) * HDIM + h]      = acc0[j] + bv;
        out[(size_t)(g * 32 + 16 + lhi * 4 + j) * HDIM + h] = acc1[j] + bv;
    }
}

/* ---------- slow fallback (only if ws too small) ---------- */
__global__ __launch_bounds__(256) void build_veff_plain(
        const float* __restrict__ W, const float* __restrict__ Wc,
        float* __restrict__ veff) {
    int idx = blockIdx.x * 256 + threadIdx.x;
    int c = idx >> 7, h = idx & 127;
    float acc = 0.f;
#pragma unroll
    for (int b = 0; b < NBASE; ++b)
        acc += Wc[(c & 15) * NBASE + b] * W[(b * DIM + (c >> 4)) * HDIM + h];
    veff[c * HDIM + h] = acc;
}
__global__ __launch_bounds__(256) void init_out_bias(
        const float* __restrict__ bias, float* __restrict__ out) {
    int idx = blockIdx.x * 256 + threadIdx.x;
    if (idx < N_NODES * HDIM) out[idx] = bias[idx & 127];
}
__global__ __launch_bounds__(128) void edge_slow(
        const float* __restrict__ vertex, const float* __restrict__ eval,
        const int* __restrict__ esrc, const int* __restrict__ edst,
        const int* __restrict__ erel, const float* __restrict__ veff,
        float* __restrict__ out) {
    int e = blockIdx.x;
    int h = threadIdx.x;
    __shared__ float vrow[DIM];
    int src = esrc[e], dst = edst[e], rel = erel[e];
    float val = eval[e];
    if (h < DIM) vrow[h] = vertex[(size_t)src * DIM + h];
    __syncthreads();
    float acc = 0.f;
#pragma unroll 8
    for (int d = 0; d < DIM; ++d)
        acc += vrow[d] * veff[(rel * DIM + d) * HDIM + h];
    atomicAdd(out + (size_t)dst * HDIM + h, val * acc);
}

extern "C" void kernel_launch(void* const* d_in, const int* in_sizes, int n_in,
                              void* d_out, int out_size, void* d_ws, size_t ws_size,
                              hipStream_t stream) {
    const float* vertex   = (const float*)d_in[0];
    const float* edge_val = (const float*)d_in[1];
    const float* W        = (const float*)d_in[2];
    const float* W_comp   = (const float*)d_in[3];
    const float* B        = (const float*)d_in[4];
    const int*   edge_src = (const int*)d_in[5];
    const int*   edge_dst = (const int*)d_in[6];
    const int*   edge_rel = (const int*)d_in[7];
    float* out = (float*)d_out;

    if (ws_size >= WS_NEED) {
        __hip_bfloat16* veff = (__hip_bfloat16*)((char*)d_ws + OFF_VEFF);
        unsigned* vtxb = (unsigned*)((char*)d_ws + OFF_VTXB);
        int*   bcur  = (int*)((char*)d_ws + OFF_BCUR);
        int*   nofs  = (int*)((char*)d_ws + OFF_NOFS);
        uint2* recs1 = (uint2*)((char*)d_ws + OFF_REC1);
        uint2* recs2 = (uint2*)((char*)d_ws + OFF_REC2);

        prologue<<<PRO_BLKS, 256, 0, stream>>>(W, W_comp, veff, vertex, vtxb, bcur);
        pass1_scatter<<<P1_BLOCKS, 256, 0, stream>>>(
            edge_src, edge_dst, edge_rel, edge_val, bcur, recs1);
        pass2_scatter<<<NCB, 256, 0, stream>>>(recs1, bcur, nofs, recs2);
        fused_agg_gemm<<<N_NODES / 32, 512, 0, stream>>>(
            (const unsigned short*)vtxb, recs2, nofs, veff, B, out);
    } else {
        float* veff = (float*)d_ws;
        build_veff_plain<<<KDIM * HDIM / 256, 256, 0, stream>>>(W, W_comp, veff);
        init_out_bias<<<(N_NODES * HDIM + 255) / 256, 256, 0, stream>>>(B, out);
        edge_slow<<<NEDGE, 128, 0, stream>>>(
            vertex, edge_val, edge_src, edge_dst, edge_rel, veff, out);
    }
}